// Round 17
// baseline (264.685 us; speedup 1.0000x reference)
//
#include <hip/hip_runtime.h>
#include <hip/hip_bf16.h>

#define I_SZ 834
#define H_SZ 190
#define F_SZ 250
#define O_SZ 512
#define T_SZ 256
#define K_SZ 1024   // I+H
#define NW   47500  // F*H: Wupd flat IS W3[1024][47500] row-major

typedef __attribute__((ext_vector_type(8))) short short8;
typedef __attribute__((ext_vector_type(4))) float f32x4;

__device__ __forceinline__ short f2bf(float f) {
    union { __hip_bfloat16 h; short s; } u;
    u.h = __float2bfloat16(f);
    return u.s;
}
__device__ __forceinline__ float bf2f(short s) {
    union { short s; __hip_bfloat16 h; } u;
    u.s = s;
    return __bfloat162float(u.h);
}

__device__ __forceinline__ void gll16(const void* g, void* l) {
    __builtin_amdgcn_global_load_lds(
        (const __attribute__((address_space(1))) void*)g,
        (__attribute__((address_space(3))) void*)l, 16, 0, 0);
}

__device__ __forceinline__ void lds_barrier() {
    asm volatile("s_waitcnt lgkmcnt(0)" ::: "memory");
    __builtin_amdgcn_s_barrier();
}

__device__ __forceinline__ float fast_tanh(float x) {
    const float e = __expf(2.f * x);
    return 1.f - 2.f / (e + 1.f);
}

// -------- K2b: slabs + zeroing (incl. flag) ---------------------------------
__global__ void __launch_bounds__(256) k2b_buildAx(const float* __restrict__ x,
                                                   const float* __restrict__ W1,
                                                   const float* __restrict__ bupd,
                                                   const float* __restrict__ W2,
                                                   const float* __restrict__ Wrnn,
                                                   short* __restrict__ Abf2,
                                                   float* __restrict__ zprime,
                                                   float* __restrict__ W1p,
                                                   float* __restrict__ bupdp,
                                                   short* __restrict__ W2s,
                                                   short* __restrict__ Wxs,
                                                   unsigned int* __restrict__ flag) {
    const int t = blockIdx.x;
    const int c = threadIdx.x;
    if (t == 0 && c == 0) *flag = 0u;         // reset scan-done flag every call
    for (int i = c; i < I_SZ; i += 256)
        Abf2[(i >> 3) * (T_SZ * 8) + t * 8 + (i & 7)] = f2bf(x[t * I_SZ + i]);
    for (int i = I_SZ + c; i < 864; i += 256)
        Abf2[(i >> 3) * (T_SZ * 8) + t * 8 + (i & 7)] = 0;
    for (int j = c; j < F_SZ; j += 256)
        zprime[t * F_SZ + j] = 0.f;
    #pragma unroll
    for (int rr = 0; rr < 4; ++rr) {
        const int r = t * 4 + rr;
        W1p[r * 256 + c]   = (c < F_SZ) ? W1[r * F_SZ + c] : 0.f;
        bupdp[r * 256 + c] = (c < F_SZ) ? bupd[r * F_SZ + c] : 0.f;
    }
    {
        const int j = t;
        #pragma unroll
        for (int rep = 0; rep < 2; ++rep) {
            const int o = c + rep * 256;
            W2s[(j >> 3) * (O_SZ * 8) + o * 8 + (j & 7)] =
                (j < F_SZ) ? f2bf(W2[j * O_SZ + o]) : (short)0;
        }
    }
    if (t < 108 && c < 192) {
        #pragma unroll
        for (int e = 0; e < 8; ++e) {
            const int kk = t * 8 + e;
            const float v = (c < H_SZ && kk < I_SZ) ? Wrnn[c * K_SZ + H_SZ + kk] : 0.f;
            Wxs[t * 1536 + c * 8 + e] = f2bf(v);
        }
    }
}

// -------- K1 v3: P^T via MFMA, slab A-operand (validated r16) ---------------
__global__ void __launch_bounds__(256) k1_mfma(const short* __restrict__ Abf2,
                                               const short* __restrict__ Wxs,
                                               const float* __restrict__ brnn,
                                               float* __restrict__ P) {
    const int tid = threadIdx.x;
    const int bh = blockIdx.x;
    const int w = tid >> 6, l = tid & 63;
    const int l15 = l & 15, lg = l >> 4;

    f32x4 acc[4];
    #pragma unroll
    for (int tt = 0; tt < 4; ++tt) acc[tt] = (f32x4){0.f, 0.f, 0.f, 0.f};

    for (int ks = 0; ks < 27; ++ks) {
        const short8 afr = *reinterpret_cast<const short8*>(
            &Wxs[(size_t)(ks * 4 + lg) * 1536 + (size_t)(bh * 16 + l15) * 8]);
        #pragma unroll
        for (int tt = 0; tt < 4; ++tt) {
            const short* ap = Abf2 + (size_t)(ks * 4 + lg) * (T_SZ * 8)
                                   + (size_t)(w * 64 + tt * 16 + l15) * 8;
            short8 bfr = *reinterpret_cast<const short8*>(ap);
            acc[tt] = __builtin_amdgcn_mfma_f32_16x16x32_bf16(afr, bfr, acc[tt], 0, 0, 0);
        }
    }
    #pragma unroll
    for (int tt = 0; tt < 4; ++tt) {
        const int t = w * 64 + tt * 16 + l15;
        #pragma unroll
        for (int r = 0; r < 4; ++r) {
            const int hrow = bh * 16 + lg * 4 + r;
            if (hrow < H_SZ) P[t * H_SZ + hrow] = acc[tt][r] + brnn[hrow];
        }
    }
}

// -------- K23: fused scan (block 0) + staged GEMM (blocks 1..189) -----------
// Block 0: r11-validated 8-wave scan (4 n-quarters x 2 k-halves), sets flag.
// Blocks 1..186: Wupd tiles BN=256; blocks 187..189: W1p/bupd-hi/bupd-lo.
// GEMM: stages 0..25 = x-part of A (ready after k2b, runs DURING the scan);
// spin on flag (all 190 blocks co-resident: 101KB LDS -> 1 block/CU, 190<=256
// CUs -> no deadlock, order-independent); stages 26..31 = h-part + epilogue.
__global__ void __launch_bounds__(512, 2) k23_fused(
        const float* __restrict__ Wrnn, const float* __restrict__ h0,
        const float* __restrict__ P, float* __restrict__ S,
        short* __restrict__ Abf2,
        const float* __restrict__ Wupd, const float* __restrict__ W1p,
        const float* __restrict__ bupdp,
        float* __restrict__ zprime, float* __restrict__ d1,
        float* __restrict__ d2h, float* __restrict__ d2l,
        unsigned int* __restrict__ flag) {
    __shared__ __align__(16) float Wlds[2][32 * 256];   // 64 KB
    __shared__ __align__(16) short Alds[2][8192];       // 32 KB
    __shared__ float part3[3][256];                     //  3 KB
    __shared__ __align__(16) short hlds[2][192];
    __shared__ float spart[2][192];

    const int tid = threadIdx.x;
    const int bid = blockIdx.x;
    const int l = tid & 63;
    const int l15 = l & 15, lg = l >> 4;

    if (bid == 0) {
        // ---------------- scan (r11 v5 structure, fast_tanh) ----------------
        const int w = tid >> 6;
        const int wn = w & 3, wk = w >> 2;
        const short8 zs = {0, 0, 0, 0, 0, 0, 0, 0};
        short8 B[3][3];
        #pragma unroll
        for (int kt = 0; kt < 3; ++kt)
            #pragma unroll
            for (int nt = 0; nt < 3; ++nt) {
                const int n = wn * 48 + nt * 16 + l15;
                short8 bf = zs;
                #pragma unroll
                for (int e = 0; e < 8; ++e) {
                    const int kk = wk * 96 + kt * 32 + lg * 8 + e;
                    float v = (n < H_SZ && kk < H_SZ) ? Wrnn[n * K_SZ + kk] : 0.f;
                    bf[e] = f2bf(v);
                }
                B[kt][nt] = bf;
            }
        if (tid < 192) {
            hlds[0][tid] = f2bf((tid < H_SZ) ? h0[tid] : 0.f);
            hlds[1][tid] = 0;
        }
        float Srun = 0.f;
        float pc = (tid < H_SZ) ? P[tid] : 0.f;
        lds_barrier();

        int rb = 0;
        #pragma unroll 1
        for (int t = 0; t < T_SZ; ++t) {
            short8 a[3];
            #pragma unroll
            for (int kt = 0; kt < 3; ++kt) {
                short8 ar = *reinterpret_cast<const short8*>(
                    &hlds[rb][wk * 96 + kt * 32 + lg * 8]);
                a[kt] = (l15 == 0) ? ar : zs;
            }
            const float pn = (t + 1 < T_SZ && tid < H_SZ) ? P[(t + 1) * H_SZ + tid] : 0.f;
            f32x4 acc[3];
            #pragma unroll
            for (int nt = 0; nt < 3; ++nt) {
                f32x4 c4 = {0.f, 0.f, 0.f, 0.f};
                #pragma unroll
                for (int kt = 0; kt < 3; ++kt)
                    c4 = __builtin_amdgcn_mfma_f32_16x16x32_bf16(a[kt], B[kt][nt], c4, 0, 0, 0);
                acc[nt] = c4;
            }
            if (l < 16) {
                #pragma unroll
                for (int nt = 0; nt < 3; ++nt)
                    spart[wk][wn * 48 + nt * 16 + l] = acc[nt][0];
            }
            lds_barrier();
            if (tid < H_SZ) {
                const float v = fast_tanh(spart[0][tid] + spart[1][tid] + pc);
                S[t * H_SZ + tid] = Srun;            // prefix EXCLUDING current
                const int k = I_SZ + tid;
                Abf2[(k >> 3) * (T_SZ * 8) + t * 8 + (k & 7)] = f2bf(v);
                hlds[rb ^ 1][tid] = f2bf(v);
                Srun += v;
            }
            lds_barrier();
            rb ^= 1;
            pc = pn;
        }
        __threadfence();                             // release S + Abf2-h
        if (tid == 0) atomicExch(flag, 1u);
        return;
    }

    // ---------------- GEMM blocks ----------------
    const bool mainb = bid <= 186;
    const int role = mainb ? 0 : (bid - 187);        // 0:W1p 1:bupd-hi 2:bupd-lo
    const bool isLo = (!mainb) && (role == 2);
    const float* Wsrc = mainb ? Wupd : ((role == 0) ? W1p : bupdp);
    const long long stride = mainb ? NW : 256;
    const int ncols = mainb ? NW : 256;
    const int bn0 = mainb ? (bid - 1) * 256 : 0;
    const int wv = tid >> 6;

    for (int i = tid; i < 768; i += 512) (&part3[0][0])[i] = 0.f;

    // staging: 48 chunks of 1KB (32 W rows + 16 A sub-slabs), 6 per wave
    const char* src[6];
    long long stp[6];
    int cloc[6];
    #pragma unroll
    for (int i = 0; i < 6; ++i) {
        const int c = wv * 6 + i;
        cloc[i] = c;
        if (c < 32) {                                // W: row c, cols l*4..+3
            const int col = l * 4;
            const bool ok = (bn0 + col + 4) <= ncols;   // ncols % 4 == 0
            src[i] = (const char*)(Wsrc + (size_t)c * stride + (size_t)(ok ? (bn0 + col) : bn0));
            stp[i] = 32LL * stride * 4;
        } else {                                     // A: chunk ca of 4 slabs
            const int ca = c - 32;
            src[i] = (const char*)(Abf2 + (size_t)ca * 512 + (size_t)l * 8);
            stp[i] = 16384;
        }
    }

    f32x4 acc[2][16];
    #pragma unroll
    for (int hf = 0; hf < 2; ++hf)
        #pragma unroll
        for (int tt = 0; tt < 16; ++tt) acc[hf][tt] = (f32x4){0.f, 0.f, 0.f, 0.f};

#define K23_ISSUE(BUF) do {                                                    \
        _Pragma("unroll")                                                      \
        for (int i = 0; i < 6; ++i) {                                          \
            void* dst = (cloc[i] < 32) ? (void*)&Wlds[BUF][cloc[i] * 256]      \
                                       : (void*)&Alds[BUF][(cloc[i] - 32) * 512]; \
            gll16(src[i], dst);                                                \
            src[i] += stp[i];                                                  \
        }                                                                      \
    } while (0)

#define K23_COMPUTE(BUF) do {                                                  \
        short8 afr0, afr1;                                                     \
        _Pragma("unroll")                                                      \
        for (int e = 0; e < 8; ++e) {                                          \
            const float v0 = Wlds[BUF][(lg * 8 + e) * 256 + wv * 16 + l15];    \
            const float v1 = Wlds[BUF][(lg * 8 + e) * 256 + 128 + wv * 16 + l15]; \
            if (isLo) {                                                        \
                afr0[e] = f2bf(v0 - bf2f(f2bf(v0)));                           \
                afr1[e] = f2bf(v1 - bf2f(f2bf(v1)));                           \
            } else {                                                           \
                afr0[e] = f2bf(v0);                                            \
                afr1[e] = f2bf(v1);                                            \
            }                                                                  \
        }                                                                      \
        _Pragma("unroll")                                                      \
        for (int tt = 0; tt < 16; ++tt) {                                      \
            short8 bfr = *reinterpret_cast<const short8*>(                     \
                &Alds[BUF][((size_t)lg * 256 + tt * 16 + l15) * 8]);           \
            acc[0][tt] = __builtin_amdgcn_mfma_f32_16x16x32_bf16(afr0, bfr, acc[0][tt], 0, 0, 0); \
            acc[1][tt] = __builtin_amdgcn_mfma_f32_16x16x32_bf16(afr1, bfr, acc[1][tt], 0, 0, 0); \
        }                                                                      \
    } while (0)

    // segment 1: stages 0..25 (k 0..831 = x-part, no scan dependency)
    K23_ISSUE(0);
    __syncthreads();
    int cur = 0;
    #pragma unroll 1
    for (int s = 0; s < 26; ++s) {
        if (s < 25) K23_ISSUE(cur ^ 1);
        K23_COMPUTE(cur);
        __syncthreads();
        cur ^= 1;
    }

    // wait for scan (S + Abf2 h-slabs). All blocks co-resident -> safe spin.
    if (tid == 0) {
        while (atomicAdd(flag, 0u) == 0u) __builtin_amdgcn_s_sleep(32);
    }
    __syncthreads();
    __threadfence();

    // segment 2: stages 26..31 (k 832..1023 = h-part)
    K23_ISSUE(cur);
    __syncthreads();
    #pragma unroll 1
    for (int s = 26; s < 32; ++s) {
        if (s < 31) K23_ISSUE(cur ^ 1);
        K23_COMPUTE(cur);
        __syncthreads();
        cur ^= 1;
    }
#undef K23_ISSUE
#undef K23_COMPUTE

    if (mainb) {
        const int jlo = bn0 / H_SZ;
        #pragma unroll
        for (int hf = 0; hf < 2; ++hf) {
            #pragma unroll
            for (int tt = 0; tt < 16; ++tt) {
                float p0 = 0.f, p1 = 0.f, p2 = 0.f;
                const int t = tt * 16 + l15;
                #pragma unroll
                for (int r = 0; r < 4; ++r) {
                    const int n = bn0 + hf * 128 + wv * 16 + lg * 4 + r;
                    const bool ok = n < NW;
                    const int nc = ok ? n : NW - 1;
                    const int j = nc / H_SZ;
                    const int h = nc - j * H_SZ;
                    const float prod = ok ? acc[hf][tt][r] * S[t * H_SZ + h] : 0.f;
                    const int b = j - jlo;
                    if (b == 0) p0 += prod;
                    else if (b == 1) p1 += prod;
                    else p2 += prod;
                }
                p0 += __shfl_xor(p0, 16, 64); p0 += __shfl_xor(p0, 32, 64);
                p1 += __shfl_xor(p1, 16, 64); p1 += __shfl_xor(p1, 32, 64);
                p2 += __shfl_xor(p2, 16, 64); p2 += __shfl_xor(p2, 32, 64);
                if (lg == 0) {
                    if (p0 != 0.f) atomicAdd(&part3[0][t], p0);
                    if (p1 != 0.f) atomicAdd(&part3[1][t], p1);
                    if (p2 != 0.f) atomicAdd(&part3[2][t], p2);
                }
            }
        }
        __syncthreads();
        for (int i = tid; i < 768; i += 512) {
            const int b = i >> 8, t = i & 255;
            const int j = jlo + b;
            const float v = part3[b][t];
            if (j < F_SZ && v != 0.f) atomicAdd(&zprime[t * F_SZ + j], v);
        }
    } else {
        float* dst = (role == 0) ? d1 : ((role == 1) ? d2h : d2l);
        #pragma unroll
        for (int hf = 0; hf < 2; ++hf)
            #pragma unroll
            for (int tt = 0; tt < 16; ++tt) {
                const int t = tt * 16 + l15;
                #pragma unroll
                for (int r = 0; r < 4; ++r) {
                    const int n = hf * 128 + wv * 16 + lg * 4 + r;
                    dst[t * 256 + n] = acc[hf][tt][r];
                }
            }
    }
}

// -------- K4e: z = zprime + d1 + t*(d2h+d2l) + b1 -> SELU -> ysb slab -------
__global__ void __launch_bounds__(256) k4e_selu(const float* __restrict__ zprime,
                                                const float* __restrict__ d1,
                                                const float* __restrict__ d2h,
                                                const float* __restrict__ d2l,
                                                const float* __restrict__ b1,
                                                short* __restrict__ ysb) {
    const int t = blockIdx.x;
    const int j = threadIdx.x;
    short sv = 0;
    if (j < F_SZ) {
        const float d2 = d2h[t * 256 + j] + d2l[t * 256 + j];
        float z = zprime[t * F_SZ + j] + d1[t * 256 + j] + (float)t * d2 + b1[j];
        const float scale = 1.0507009873554805f, alpha = 1.6732632423543772f;
        float y = z > 0.f ? scale * z : scale * alpha * (expf(z) - 1.f);
        sv = f2bf(y);
    }
    ysb[(j >> 3) * (T_SZ * 8) + t * 8 + (j & 7)] = sv;
}

// -------- K4b v3: slab A-operand (validated r16) ----------------------------
__global__ void __launch_bounds__(64) k4b_mfma(const short* __restrict__ ysb,
                                               const short* __restrict__ W2s,
                                               const float* __restrict__ b2,
                                               float* __restrict__ out) {
    const int l = threadIdx.x;
    const int o0 = (blockIdx.x & 31) * 16;
    const int th = blockIdx.x >> 5;
    const int l15 = l & 15, lg = l >> 4;
    const int o = o0 + l15;

    f32x4 acc[2];
    acc[0] = (f32x4){0.f, 0.f, 0.f, 0.f};
    acc[1] = (f32x4){0.f, 0.f, 0.f, 0.f};

    #pragma unroll
    for (int ks = 0; ks < 8; ++ks) {
        const short8 afr = *reinterpret_cast<const short8*>(
            &W2s[(size_t)(ks * 4 + lg) * (O_SZ * 8) + (size_t)o * 8]);
        #pragma unroll
        for (int tt = 0; tt < 2; ++tt) {
            const short* ap = ysb + (size_t)(ks * 4 + lg) * (T_SZ * 8)
                                  + (size_t)(th * 32 + tt * 16 + l15) * 8;
            short8 bfr = *reinterpret_cast<const short8*>(ap);
            acc[tt] = __builtin_amdgcn_mfma_f32_16x16x32_bf16(afr, bfr, acc[tt], 0, 0, 0);
        }
    }
    #pragma unroll
    for (int tt = 0; tt < 2; ++tt) {
        const int t = th * 32 + tt * 16 + l15;
        #pragma unroll
        for (int r = 0; r < 4; ++r) {
            const int oo = o0 + lg * 4 + r;
            out[t * O_SZ + oo] = acc[tt][r] + b2[oo];
        }
    }
}

extern "C" void kernel_launch(void* const* d_in, const int* in_sizes, int n_in,
                              void* d_out, int out_size, void* d_ws, size_t ws_size,
                              hipStream_t stream) {
    const float* x    = (const float*)d_in[0];
    const float* h0   = (const float*)d_in[1];
    const float* Wrnn = (const float*)d_in[2];
    const float* brnn = (const float*)d_in[3];
    const float* Wupd = (const float*)d_in[4];
    const float* bupd = (const float*)d_in[5];
    const float* W1   = (const float*)d_in[6];
    const float* b1   = (const float*)d_in[7];
    const float* W2   = (const float*)d_in[8];
    const float* b2   = (const float*)d_in[9];
    float* out = (float*)d_out;

    float* ws = (float*)d_ws;
    float* P      = ws;                              // 48640 f
    float* S      = P + T_SZ * H_SZ;                 // 48640 f
    float* zprime = S + T_SZ * H_SZ;                 // 64000 f
    short* Abf2   = (short*)(zprime + T_SZ * F_SZ);  // 262144 s (512 KB)
    short* ysb    = Abf2 + 262144;                   // 65536 s (128 KB)
    float* d1     = (float*)(ysb + 65536);           // 65536 f
    float* d2h    = d1 + 65536;                      // 65536 f
    float* d2l    = d2h + 65536;                     // 65536 f
    float* W1p    = d2l + 65536;                     // 262144 f (1 MB)
    float* bupdp  = W1p + 262144;                    // 262144 f (1 MB)
    short* W2s    = (short*)(bupdp + 262144);        // 131072 s (256 KB)
    short* Wxs    = W2s + 131072;                    // 165888 s (324 KB)
    unsigned int* flag = (unsigned int*)(Wxs + 165888);

    k2b_buildAx<<<T_SZ, 256, 0, stream>>>(x, W1, bupd, W2, Wrnn,
                                          Abf2, zprime, W1p, bupdp, W2s, Wxs, flag);
    k1_mfma    <<<12,   256, 0, stream>>>(Abf2, Wxs, brnn, P);
    k23_fused  <<<190,  512, 0, stream>>>(Wrnn, h0, P, S, Abf2,
                                          Wupd, W1p, bupdp, zprime, d1, d2h, d2l, flag);
    k4e_selu   <<<T_SZ, 256, 0, stream>>>(zprime, d1, d2h, d2l, b1, ysb);
    k4b_mfma   <<<256,  64,  0, stream>>>(ysb, W2s, b2, out);
}